// Round 10
// baseline (191.268 us; speedup 1.0000x reference)
//
#include <hip/hip_runtime.h>

// x (64,3,512,512) f32, mean_params (64,4) f32.
#define BB 64
#define CC 3
#define HH 512
#define WW 512
#define HW (HH * WW)           // 262144
#define CHW (CC * HW)          // 786432

#define PROWS 64               // max staged rows
#define PSTRIDE 68             // LDS row stride in floats; 68 % 32 == 4 -> bank spread

typedef float f2_t __attribute__((ext_vector_type(2), aligned(4)));
typedef float f4_t __attribute__((ext_vector_type(4), aligned(16)));

// R6 skeleton (champion, 64.6us): shared geometry, per-channel patch in ONE
// 17.4KB LDS buffer, 8 blocks/CU (= 32 waves/CU, the HW cap), 5 syncs.
// Change: ALL 3 channels' staging loads issue upfront into registers (12x f4),
// latency paid once under geometry; each channel phase is then pure LDS/VALU
// with zero HBM round-trips. Affine coeffs inlined (no prep launch).
__global__ __launch_bounds__(256, 8) void affine_sample_kernel(
    const float* __restrict__ x,
    const float* __restrict__ mp,
    float* __restrict__ out)
{
    __shared__ float smem[PROWS * PSTRIDE];      // 17408 B

    int tid  = threadIdx.x;
    int lane = tid & 63;
    int wid  = tid >> 6;
    int strip = lane & 7;
    int lrow  = lane >> 3;

    int bidx = blockIdx.x;          // [b:6][tile:8]
    int b    = bidx >> 8;
    int rem  = bidx & 255;
    int tileH = (rem >> 4) << 5;
    int tileW = (rem & 15) << 5;

    int h  = tileH + (wid << 3) + lrow;
    int w0 = tileW + (strip << 2);

    // ---- per-batch affine coefficients in PIXEL space (wave-uniform)
    float theta = mp[b * 4 + 0];
    float scl   = mp[b * 4 + 1];
    float tx    = mp[b * 4 + 2];
    float ty    = mp[b * 4 + 3];
    float sn, cs;
    sincosf(theta, &sn, &cs);
    float ct = scl * cs;
    float st = scl * sn;
    const float dd = -255.5f;                    // 256*xs at w=0
    float Cx = dd * (ct - st) + 256.0f * tx + 255.5f;
    float Cy = dd * (st + ct) + 256.0f * ty + 255.5f;

    // ---- block-uniform source bbox from tile corners
    float wA = (float)tileW, wB = (float)(tileW + 31);
    float hA = (float)tileH, hB = (float)(tileH + 31);
    float cwA = ct * wA, cwB = ct * wB, shA = st * hA, shB = st * hB;
    float ixmin = fminf(cwA, cwB) - fmaxf(shA, shB) + Cx;
    float ixmax = fmaxf(cwA, cwB) - fminf(shA, shB) + Cx;
    float swA = st * wA, swB = st * wB, chA = ct * hA, chB = ct * hB;
    float iymin = fminf(swA, swB) + fminf(chA, chB) + Cy;
    float iymax = fmaxf(swA, swB) + fmaxf(chA, chB) + Cy;

    int bx_lo = (int)floorf(ixmin) - 1;          // +-1: ulp-drift margin
    int bx_hi = (int)floorf(ixmax) + 2;
    int by_lo = (int)floorf(iymin) - 1;
    int by_hi = (int)floorf(iymax) + 2;
    int px_lo = min(max(bx_lo, 0), WW - 2);
    int px_hi = min(max(bx_hi - 1, 0), WW - 2) + 1;
    int py_lo = min(max(by_lo, 0), HH - 2);
    int py_hi = min(max(by_hi - 1, 0), HH - 2) + 1;
    int By = py_hi - py_lo + 1;

    int ax_lo = px_lo & ~3;                      // 16B-aligned window start
    if (ax_lo > WW - 64) ax_lo = WW - 64;        // keep 64-col window in-bounds
    bool staged = ((px_hi - ax_lo) <= 63) && (By <= PROWS);

    const float* plane0 = x + b * CHW;
    const float* srcb   = plane0 + py_lo * WW + ax_lo;

    int r0 = tid >> 4;                           // 0..15 staging row
    int c4 = (tid & 15) << 2;                    // 0,4,...,60 staging col

    // ---- upfront staging loads: ALL 3 channels into registers (12x f4).
    // Latency of the whole burst is paid once, hidden under geometry below.
    f4_t rg[CC][4];
    bool g0 = false, g1 = false, g2 = false, g3 = false;
    if (staged) {
        g0 = (r0      < By);
        g1 = (r0 + 16 < By);
        g2 = (r0 + 32 < By);
        g3 = (r0 + 48 < By);
#pragma unroll
        for (int ch = 0; ch < CC; ++ch) {
            const float* s = srcb + ch * HW;
            rg[ch][0] = g0 ? *(const f4_t*)(s +  r0       * WW + c4) : (f4_t){0,0,0,0};
            rg[ch][1] = g1 ? *(const f4_t*)(s + (r0 + 16) * WW + c4) : (f4_t){0,0,0,0};
            rg[ch][2] = g2 ? *(const f4_t*)(s + (r0 + 32) * WW + c4) : (f4_t){0,0,0,0};
            rg[ch][3] = g3 ? *(const f4_t*)(s + (r0 + 48) * WW + c4) : (f4_t){0,0,0,0};
        }
    }

    // ---- per-pixel geometry (incremental along the 4-px strip; shared by 3 ch)
    float ix = ct * (float)w0 - st * (float)h + Cx;
    float iy = st * (float)w0 + ct * (float)h + Cy;

    float al[4], ar[4], f0[4], f1[4];
    int o0[4], o1[4];
#pragma unroll
    for (int p = 0; p < 4; ++p) {
        float x0f = floorf(ix), y0f = floorf(iy);
        float fx = ix - x0f,    fy = iy - y0f;
        int x0 = (int)x0f, y0 = (int)y0f;
        int y1 = y0 + 1;

        bool xin = (x0 >= 0) & (x0 <= WW - 2);
        float wl = 1.0f - fx;
        al[p] = xin ? wl : ((x0 == -1)     ? fx : 0.0f);
        ar[p] = xin ? fx : ((x0 == WW - 1) ? wl : 0.0f);
        int base = min(max(x0, 0), WW - 2);

        bool vy0 = (y0 >= 0) & (y0 < HH);
        bool vy1 = (y1 >= 0) & (y1 < HH);
        int y0c = min(max(y0, 0), HH - 1);
        int y1c = min(max(y1, 0), HH - 1);
        f0[p] = (1.0f - fy) * (float)vy0;
        f1[p] = fy          * (float)vy1;

        if (staged) {
            int lx = base - ax_lo;               // in [0,62] by construction
            o0[p] = (y0c - py_lo) * PSTRIDE + lx;
            o1[p] = (y1c - py_lo) * PSTRIDE + lx;
        } else {
            o0[p] = y0c * WW + base;
            o1[p] = y1c * WW + base;
        }
        ix += ct;
        iy += st;
    }

    float* ob = out + b * CHW + h * WW + w0;

    if (staged) {
#pragma unroll
        for (int ch = 0; ch < CC; ++ch) {
            if (ch) __syncthreads();             // protect previous blend's reads
            // drain this channel's regs -> LDS (no VMEM dependency left
            // except the upfront burst, already covered by geometry)
            if (g0) *(f4_t*)(&smem[ r0       * PSTRIDE + c4]) = rg[ch][0];
            if (g1) *(f4_t*)(&smem[(r0 + 16) * PSTRIDE + c4]) = rg[ch][1];
            if (g2) *(f4_t*)(&smem[(r0 + 32) * PSTRIDE + c4]) = rg[ch][2];
            if (g3) *(f4_t*)(&smem[(r0 + 48) * PSTRIDE + c4]) = rg[ch][3];
            __syncthreads();                     // patch ready

            f4_t v;
#pragma unroll
            for (int p = 0; p < 4; ++p) {
                float a0 = smem[o0[p]], a1 = smem[o0[p] + 1];
                float b0 = smem[o1[p]], b1 = smem[o1[p] + 1];
                v[p] = f0[p] * (al[p] * a0 + ar[p] * a1)
                     + f1[p] * (al[p] * b0 + ar[p] * b1);
            }
            __builtin_nontemporal_store(v, (f4_t*)(ob + ch * HW));
        }
    } else {
        // fallback: direct global f2 gathers (block-uniform branch, no barriers)
#pragma unroll
        for (int ch = 0; ch < CC; ++ch) {
            const float* pl = plane0 + ch * HW;
            f4_t v;
#pragma unroll
            for (int p = 0; p < 4; ++p) {
                f2_t t = *(const f2_t*)(pl + o0[p]);
                f2_t u = *(const f2_t*)(pl + o1[p]);
                v[p] = f0[p] * (al[p] * t.x + ar[p] * t.y)
                     + f1[p] * (al[p] * u.x + ar[p] * u.y);
            }
            __builtin_nontemporal_store(v, (f4_t*)(ob + ch * HW));
        }
    }
}

extern "C" void kernel_launch(void* const* d_in, const int* in_sizes, int n_in,
                              void* d_out, int out_size, void* d_ws, size_t ws_size,
                              hipStream_t stream)
{
    const float* x  = (const float*)d_in[0];
    const float* mp = (const float*)d_in[1];
    float* out = (float*)d_out;

    dim3 block(256);
    dim3 grid(BB * 256);            // 64 batches x 16x16 tiles of 32x32
    affine_sample_kernel<<<grid, block, 0, stream>>>(x, mp, out);
}

// Round 11
// 62.334 us; speedup vs baseline: 3.0684x; 3.0684x over previous
//
#include <hip/hip_runtime.h>

// x (64,3,512,512) f32, mean_params (64,4) f32.
#define BB 64
#define CC 3
#define HH 512
#define WW 512
#define HW (HH * WW)           // 262144
#define CHW (CC * HW)          // 786432

#define PROWS 64               // max staged rows
#define PSTRIDE 68             // LDS row stride in floats; 68 % 32 == 4 -> bank spread

typedef float f2_t __attribute__((ext_vector_type(2), aligned(4)));
typedef float f4_t __attribute__((ext_vector_type(4), aligned(16)));

// Per-batch affine coefficients in PIXEL space: ix = ct*w - st*h + Cx
__global__ __launch_bounds__(64) void prep_kernel(const float* __restrict__ mp,
                                                  float4* __restrict__ cf)
{
    int b = threadIdx.x;
    if (b < BB) {
        float theta = mp[b * 4 + 0];
        float scale = mp[b * 4 + 1];
        float tx    = mp[b * 4 + 2];
        float ty    = mp[b * 4 + 3];
        float s, c;
        sincosf(theta, &s, &c);
        float ct = scale * c;
        float st = scale * s;
        const float d = -255.5f;                 // 256*xs at w=0
        float Cx = d * (ct - st) + 256.0f * tx + 255.5f;
        float Cy = d * (st + ct) + 256.0f * ty + 255.5f;
        cf[b] = make_float4(ct, st, Cx, Cy);
    }
}

// R6 champion skeleton: shared geometry, per-channel patch in ONE 17.4KB LDS
// buffer, 8 blocks/CU (32 waves/CU = HW cap), {sync; stage; sync; blend}/ch.
// R11 changes (intra-phase only, zero live regs across barriers -> no spill):
//  - burst staging: 4 loads in flight, then 4 ds_writes (1 exposed RT, not 4)
//  - tight width BxA: stage only bbox columns (cuts staged L2 bytes ~40%)
__global__ __launch_bounds__(256, 8) void affine_sample_kernel(
    const float* __restrict__ x,
    const float4* __restrict__ cf,
    float* __restrict__ out)
{
    __shared__ float smem[PROWS * PSTRIDE];      // 17408 B

    int tid  = threadIdx.x;
    int lane = tid & 63;
    int wid  = tid >> 6;
    int strip = lane & 7;
    int lrow  = lane >> 3;

    int bidx = blockIdx.x;          // [b:6][tile:8]
    int b    = bidx >> 8;
    int rem  = bidx & 255;
    int tileH = (rem >> 4) << 5;
    int tileW = (rem & 15) << 5;

    int h  = tileH + (wid << 3) + lrow;
    int w0 = tileW + (strip << 2);

    float4 k = cf[b];
    float ct = k.x, st = k.y, Cx = k.z, Cy = k.w;

    // ---- block-uniform source bbox from tile corners
    float wA = (float)tileW, wB = (float)(tileW + 31);
    float hA = (float)tileH, hB = (float)(tileH + 31);
    float cwA = ct * wA, cwB = ct * wB, shA = st * hA, shB = st * hB;
    float ixmin = fminf(cwA, cwB) - fmaxf(shA, shB) + Cx;
    float ixmax = fmaxf(cwA, cwB) - fminf(shA, shB) + Cx;
    float swA = st * wA, swB = st * wB, chA = ct * hA, chB = ct * hB;
    float iymin = fminf(swA, swB) + fminf(chA, chB) + Cy;
    float iymax = fmaxf(swA, swB) + fmaxf(chA, chB) + Cy;

    int bx_lo = (int)floorf(ixmin) - 1;          // +-1: ulp-drift margin
    int bx_hi = (int)floorf(ixmax) + 2;
    int by_lo = (int)floorf(iymin) - 1;
    int by_hi = (int)floorf(iymax) + 2;
    int px_lo = min(max(bx_lo, 0), WW - 2);
    int px_hi = min(max(bx_hi - 1, 0), WW - 2) + 1;
    int py_lo = min(max(by_lo, 0), HH - 2);
    int py_hi = min(max(by_hi - 1, 0), HH - 2) + 1;
    int By = py_hi - py_lo + 1;

    int ax_lo = px_lo & ~3;                      // 16B-aligned window start
    int span  = px_hi - ax_lo;                   // cols needed minus 1
    bool staged = (span <= 63) && (By <= PROWS);
    int BxA = (span | 3) + 1;                    // tight width, mult of 4, <=64
    if (ax_lo + BxA > WW) ax_lo = WW - BxA;      // keep window in-bounds (stays aligned)

    const float* plane0 = x + b * CHW;
    const float* srcb   = plane0 + py_lo * WW + ax_lo;

    int r0 = tid >> 4;                           // 0..15 staging row
    int c4 = (tid & 15) << 2;                    // 0,4,...,60 staging col

    bool cok = c4 < BxA;                         // tight width guard
    bool g0 = cok & (r0      < By);
    bool g1 = cok & (r0 + 16 < By);
    bool g2 = cok & (r0 + 32 < By);
    bool g3 = cok & (r0 + 48 < By);

    // ---- per-pixel geometry (incremental along the 4-px strip; shared by 3 ch)
    float ix = ct * (float)w0 - st * (float)h + Cx;
    float iy = st * (float)w0 + ct * (float)h + Cy;

    float al[4], ar[4], f0[4], f1[4];
    int o0[4], o1[4];
#pragma unroll
    for (int p = 0; p < 4; ++p) {
        float x0f = floorf(ix), y0f = floorf(iy);
        float fx = ix - x0f,    fy = iy - y0f;
        int x0 = (int)x0f, y0 = (int)y0f;
        int y1 = y0 + 1;

        bool xin = (x0 >= 0) & (x0 <= WW - 2);
        float wl = 1.0f - fx;
        al[p] = xin ? wl : ((x0 == -1)     ? fx : 0.0f);
        ar[p] = xin ? fx : ((x0 == WW - 1) ? wl : 0.0f);
        int base = min(max(x0, 0), WW - 2);

        bool vy0 = (y0 >= 0) & (y0 < HH);
        bool vy1 = (y1 >= 0) & (y1 < HH);
        int y0c = min(max(y0, 0), HH - 1);
        int y1c = min(max(y1, 0), HH - 1);
        f0[p] = (1.0f - fy) * (float)vy0;
        f1[p] = fy          * (float)vy1;

        if (staged) {
            int lx = base - ax_lo;               // in [0, BxA-2]
            o0[p] = (y0c - py_lo) * PSTRIDE + lx;
            o1[p] = (y1c - py_lo) * PSTRIDE + lx;
        } else {
            o0[p] = y0c * WW + base;
            o1[p] = y1c * WW + base;
        }
        ix += ct;
        iy += st;
    }

    float* ob = out + b * CHW + h * WW + w0;

    if (staged) {
#pragma unroll
        for (int ch = 0; ch < CC; ++ch) {
            if (ch) __syncthreads();             // previous blend's reads done
            // burst staging: all 4 loads issue, then 4 ds_writes.
            // Registers live only within this phase -> no spill.
            {
                const float* s = srcb + ch * HW;
                f4_t t0 = {0,0,0,0}, t1 = {0,0,0,0}, t2 = {0,0,0,0}, t3 = {0,0,0,0};
                if (g0) t0 = *(const f4_t*)(s +  r0       * WW + c4);
                if (g1) t1 = *(const f4_t*)(s + (r0 + 16) * WW + c4);
                if (g2) t2 = *(const f4_t*)(s + (r0 + 32) * WW + c4);
                if (g3) t3 = *(const f4_t*)(s + (r0 + 48) * WW + c4);
                if (g0) *(f4_t*)(&smem[ r0       * PSTRIDE + c4]) = t0;
                if (g1) *(f4_t*)(&smem[(r0 + 16) * PSTRIDE + c4]) = t1;
                if (g2) *(f4_t*)(&smem[(r0 + 32) * PSTRIDE + c4]) = t2;
                if (g3) *(f4_t*)(&smem[(r0 + 48) * PSTRIDE + c4]) = t3;
            }
            __syncthreads();                     // patch ready

            f4_t v;
#pragma unroll
            for (int p = 0; p < 4; ++p) {
                float a0 = smem[o0[p]], a1 = smem[o0[p] + 1];
                float b0 = smem[o1[p]], b1 = smem[o1[p] + 1];
                v[p] = f0[p] * (al[p] * a0 + ar[p] * a1)
                     + f1[p] * (al[p] * b0 + ar[p] * b1);
            }
            __builtin_nontemporal_store(v, (f4_t*)(ob + ch * HW));
        }
    } else {
        // fallback: direct global f2 gathers (block-uniform branch, no barriers)
#pragma unroll
        for (int ch = 0; ch < CC; ++ch) {
            const float* pl = plane0 + ch * HW;
            f4_t v;
#pragma unroll
            for (int p = 0; p < 4; ++p) {
                f2_t t = *(const f2_t*)(pl + o0[p]);
                f2_t u = *(const f2_t*)(pl + o1[p]);
                v[p] = f0[p] * (al[p] * t.x + ar[p] * t.y)
                     + f1[p] * (al[p] * u.x + ar[p] * u.y);
            }
            __builtin_nontemporal_store(v, (f4_t*)(ob + ch * HW));
        }
    }
}

extern "C" void kernel_launch(void* const* d_in, const int* in_sizes, int n_in,
                              void* d_out, int out_size, void* d_ws, size_t ws_size,
                              hipStream_t stream)
{
    const float* x  = (const float*)d_in[0];
    const float* mp = (const float*)d_in[1];
    float* out = (float*)d_out;
    float4* cf = (float4*)d_ws;     // 1 KB scratch

    prep_kernel<<<1, 64, 0, stream>>>(mp, cf);
    dim3 block(256);
    dim3 grid(BB * 256);            // 64 batches x 16x16 tiles of 32x32
    affine_sample_kernel<<<grid, block, 0, stream>>>(x, cf, out);
}

// Round 12
// 53.855 us; speedup vs baseline: 3.5515x; 1.1574x over previous
//
#include <hip/hip_runtime.h>

// x (64,3,512,512) f32, mean_params (64,4) f32.
#define BB 64
#define CC 3
#define HH 512
#define WW 512
#define HW (HH * WW)           // 262144
#define CHW (CC * HW)          // 786432

#define PROWS 64               // max staged rows
#define PSTRIDE 68             // LDS row stride in floats; 68 % 32 == 4 -> bank spread

typedef float f2_t __attribute__((ext_vector_type(2), aligned(4)));
typedef float f4_t __attribute__((ext_vector_type(4), aligned(16)));

// Per-batch affine coefficients in PIXEL space: ix = ct*w - st*h + Cx
__global__ __launch_bounds__(64) void prep_kernel(const float* __restrict__ mp,
                                                  float4* __restrict__ cf)
{
    int b = threadIdx.x;
    if (b < BB) {
        float theta = mp[b * 4 + 0];
        float scale = mp[b * 4 + 1];
        float tx    = mp[b * 4 + 2];
        float ty    = mp[b * 4 + 3];
        float s, c;
        sincosf(theta, &s, &c);
        float ct = scale * c;
        float st = scale * s;
        const float d = -255.5f;                 // 256*xs at w=0
        float Cx = d * (ct - st) + 256.0f * tx + 255.5f;
        float Cy = d * (st + ct) + 256.0f * ty + 255.5f;
        cf[b] = make_float4(ct, st, Cx, Cy);
    }
}

// R11 champion (62.3us) + block-uniform 3-way classification:
//  OOB tiles     -> store zeros, return (translations are ~N(0,1)*256 px!)
//  interior tiles-> clamp/mask-free bilinear weights (lighter VALU)
//  else          -> R11 general path, unchanged
__global__ __launch_bounds__(256, 8) void affine_sample_kernel(
    const float* __restrict__ x,
    const float4* __restrict__ cf,
    float* __restrict__ out)
{
    __shared__ float smem[PROWS * PSTRIDE];      // 17408 B

    int tid  = threadIdx.x;
    int lane = tid & 63;
    int wid  = tid >> 6;
    int strip = lane & 7;
    int lrow  = lane >> 3;

    int bidx = blockIdx.x;          // [b:6][tile:8]
    int b    = bidx >> 8;
    int rem  = bidx & 255;
    int tileH = (rem >> 4) << 5;
    int tileW = (rem & 15) << 5;

    int h  = tileH + (wid << 3) + lrow;
    int w0 = tileW + (strip << 2);

    float4 k = cf[b];
    float ct = k.x, st = k.y, Cx = k.z, Cy = k.w;

    // ---- block-uniform source bbox from tile corners
    float wA = (float)tileW, wB = (float)(tileW + 31);
    float hA = (float)tileH, hB = (float)(tileH + 31);
    float cwA = ct * wA, cwB = ct * wB, shA = st * hA, shB = st * hB;
    float ixmin = fminf(cwA, cwB) - fmaxf(shA, shB) + Cx;
    float ixmax = fmaxf(cwA, cwB) - fminf(shA, shB) + Cx;
    float swA = st * wA, swB = st * wB, chA = ct * hA, chB = ct * hB;
    float iymin = fminf(swA, swB) + fminf(chA, chB) + Cy;
    float iymax = fmaxf(swA, swB) + fmaxf(chA, chB) + Cy;

    int bx_lo = (int)floorf(ixmin) - 1;          // +-1: ulp-drift margin
    int bx_hi = (int)floorf(ixmax) + 2;
    int by_lo = (int)floorf(iymin) - 1;
    int by_hi = (int)floorf(iymax) + 2;

    float* ob = out + b * CHW + h * WW + w0;

    // ---- class 1: fully out-of-bounds tile -> exact zeros (reference: all
    // corner masks false => w00..w11 all zero). bx_hi<=0 <=> max x1 < 0;
    // bx_lo>=511 <=> min x0 > 511 (margin makes this conservative). Same for y.
    bool oob = (bx_hi <= 0) | (bx_lo >= WW - 1) | (by_hi <= 0) | (by_lo >= HH - 1);
    if (oob) {
        const f4_t z = {0.0f, 0.0f, 0.0f, 0.0f};
#pragma unroll
        for (int ch = 0; ch < CC; ++ch)
            __builtin_nontemporal_store(z, (f4_t*)(ob + ch * HW));
        return;                                  // uniform: no barrier skipped
    }

    // ---- class 2: fully interior (incl. margin) -> no clamps/masks needed
    bool interior = (bx_lo >= 0) & (bx_hi <= WW - 1) & (by_lo >= 0) & (by_hi <= HH - 1);

    int px_lo = min(max(bx_lo, 0), WW - 2);
    int px_hi = min(max(bx_hi - 1, 0), WW - 2) + 1;
    int py_lo = min(max(by_lo, 0), HH - 2);
    int py_hi = min(max(by_hi - 1, 0), HH - 2) + 1;
    int By = py_hi - py_lo + 1;

    int ax_lo = px_lo & ~3;                      // 16B-aligned window start
    int span  = px_hi - ax_lo;                   // cols needed minus 1
    bool staged = (span <= 63) && (By <= PROWS);
    int BxA = (span | 3) + 1;                    // tight width, mult of 4, <=64
    if (ax_lo + BxA > WW) ax_lo = WW - BxA;      // keep window in-bounds (aligned)

    const float* plane0 = x + b * CHW;
    const float* srcb   = plane0 + py_lo * WW + ax_lo;

    int r0 = tid >> 4;                           // 0..15 staging row
    int c4 = (tid & 15) << 2;                    // 0,4,...,60 staging col

    bool cok = c4 < BxA;                         // tight width guard
    bool g0 = cok & (r0      < By);
    bool g1 = cok & (r0 + 16 < By);
    bool g2 = cok & (r0 + 32 < By);
    bool g3 = cok & (r0 + 48 < By);

    // ---- per-pixel geometry (incremental along the 4-px strip; shared by 3 ch)
    float ix = ct * (float)w0 - st * (float)h + Cx;
    float iy = st * (float)w0 + ct * (float)h + Cy;

    float al[4], ar[4], f0[4], f1[4];
    int o0[4], o1[4];

    if (interior) {
        // pure bilinear: every corner valid, no clamps
#pragma unroll
        for (int p = 0; p < 4; ++p) {
            float x0f = floorf(ix), y0f = floorf(iy);
            float fx = ix - x0f,    fy = iy - y0f;
            int x0 = (int)x0f, y0 = (int)y0f;
            al[p] = 1.0f - fx;
            ar[p] = fx;
            f0[p] = 1.0f - fy;
            f1[p] = fy;
            if (staged) {
                int lx = x0 - ax_lo;
                o0[p] = (y0     - py_lo) * PSTRIDE + lx;
                o1[p] = (y0 + 1 - py_lo) * PSTRIDE + lx;
            } else {
                o0[p] =  y0      * WW + x0;
                o1[p] = (y0 + 1) * WW + x0;
            }
            ix += ct;
            iy += st;
        }
    } else {
        // general: clamp + mask-folded coefficients (exact reference semantics)
#pragma unroll
        for (int p = 0; p < 4; ++p) {
            float x0f = floorf(ix), y0f = floorf(iy);
            float fx = ix - x0f,    fy = iy - y0f;
            int x0 = (int)x0f, y0 = (int)y0f;
            int y1 = y0 + 1;

            bool xin = (x0 >= 0) & (x0 <= WW - 2);
            float wl = 1.0f - fx;
            al[p] = xin ? wl : ((x0 == -1)     ? fx : 0.0f);
            ar[p] = xin ? fx : ((x0 == WW - 1) ? wl : 0.0f);
            int base = min(max(x0, 0), WW - 2);

            bool vy0 = (y0 >= 0) & (y0 < HH);
            bool vy1 = (y1 >= 0) & (y1 < HH);
            int y0c = min(max(y0, 0), HH - 1);
            int y1c = min(max(y1, 0), HH - 1);
            f0[p] = (1.0f - fy) * (float)vy0;
            f1[p] = fy          * (float)vy1;

            if (staged) {
                int lx = base - ax_lo;           // in [0, BxA-2]
                o0[p] = (y0c - py_lo) * PSTRIDE + lx;
                o1[p] = (y1c - py_lo) * PSTRIDE + lx;
            } else {
                o0[p] = y0c * WW + base;
                o1[p] = y1c * WW + base;
            }
            ix += ct;
            iy += st;
        }
    }

    if (staged) {
#pragma unroll
        for (int ch = 0; ch < CC; ++ch) {
            if (ch) __syncthreads();             // previous blend's reads done
            // burst staging: all 4 loads issue, then 4 ds_writes (no spill:
            // registers live only within this phase)
            {
                const float* s = srcb + ch * HW;
                f4_t t0 = {0,0,0,0}, t1 = {0,0,0,0}, t2 = {0,0,0,0}, t3 = {0,0,0,0};
                if (g0) t0 = *(const f4_t*)(s +  r0       * WW + c4);
                if (g1) t1 = *(const f4_t*)(s + (r0 + 16) * WW + c4);
                if (g2) t2 = *(const f4_t*)(s + (r0 + 32) * WW + c4);
                if (g3) t3 = *(const f4_t*)(s + (r0 + 48) * WW + c4);
                if (g0) *(f4_t*)(&smem[ r0       * PSTRIDE + c4]) = t0;
                if (g1) *(f4_t*)(&smem[(r0 + 16) * PSTRIDE + c4]) = t1;
                if (g2) *(f4_t*)(&smem[(r0 + 32) * PSTRIDE + c4]) = t2;
                if (g3) *(f4_t*)(&smem[(r0 + 48) * PSTRIDE + c4]) = t3;
            }
            __syncthreads();                     // patch ready

            f4_t v;
#pragma unroll
            for (int p = 0; p < 4; ++p) {
                float a0 = smem[o0[p]], a1 = smem[o0[p] + 1];
                float b0 = smem[o1[p]], b1 = smem[o1[p] + 1];
                v[p] = f0[p] * (al[p] * a0 + ar[p] * a1)
                     + f1[p] * (al[p] * b0 + ar[p] * b1);
            }
            __builtin_nontemporal_store(v, (f4_t*)(ob + ch * HW));
        }
    } else {
        // fallback: direct global f2 gathers (block-uniform branch, no barriers)
#pragma unroll
        for (int ch = 0; ch < CC; ++ch) {
            const float* pl = plane0 + ch * HW;
            f4_t v;
#pragma unroll
            for (int p = 0; p < 4; ++p) {
                f2_t t = *(const f2_t*)(pl + o0[p]);
                f2_t u = *(const f2_t*)(pl + o1[p]);
                v[p] = f0[p] * (al[p] * t.x + ar[p] * t.y)
                     + f1[p] * (al[p] * u.x + ar[p] * u.y);
            }
            __builtin_nontemporal_store(v, (f4_t*)(ob + ch * HW));
        }
    }
}

extern "C" void kernel_launch(void* const* d_in, const int* in_sizes, int n_in,
                              void* d_out, int out_size, void* d_ws, size_t ws_size,
                              hipStream_t stream)
{
    const float* x  = (const float*)d_in[0];
    const float* mp = (const float*)d_in[1];
    float* out = (float*)d_out;
    float4* cf = (float4*)d_ws;     // 1 KB scratch

    prep_kernel<<<1, 64, 0, stream>>>(mp, cf);
    dim3 block(256);
    dim3 grid(BB * 256);            // 64 batches x 16x16 tiles of 32x32
    affine_sample_kernel<<<grid, block, 0, stream>>>(x, cf, out);
}

// Round 13
// 52.680 us; speedup vs baseline: 3.6307x; 1.0223x over previous
//
#include <hip/hip_runtime.h>

// x (64,3,512,512) f32, mean_params (64,4) f32.
#define BB 64
#define CC 3
#define HH 512
#define WW 512
#define HW (HH * WW)           // 262144
#define CHW (CC * HW)          // 786432

#define PROWS 64               // max staged rows (per-channel restage path)
#define PSTRIDE 68             // LDS row stride; 68 % 32 == 4 -> bank spread
#define SMEMF (PROWS * PSTRIDE) // 4352 floats = 17408 B

typedef float f2_t __attribute__((ext_vector_type(2), aligned(4)));
typedef float f4_t __attribute__((ext_vector_type(4), aligned(16)));

// Per-batch affine coefficients in PIXEL space: ix = ct*w - st*h + Cx
__global__ __launch_bounds__(64) void prep_kernel(const float* __restrict__ mp,
                                                  float4* __restrict__ cf)
{
    int b = threadIdx.x;
    if (b < BB) {
        float theta = mp[b * 4 + 0];
        float scale = mp[b * 4 + 1];
        float tx    = mp[b * 4 + 2];
        float ty    = mp[b * 4 + 3];
        float s, c;
        sincosf(theta, &s, &c);
        float ct = scale * c;
        float st = scale * s;
        const float d = -255.5f;                 // 256*xs at w=0
        float Cx = d * (ct - st) + 256.0f * tx + 255.5f;
        float Cy = d * (st + ct) + 256.0f * ty + 255.5f;
        cf[b] = make_float4(ct, st, Cx, Cy);
    }
}

// 4-way block-uniform classification:
//  OOB      -> store zeros, return
//  compact  -> ALL 3 channels staged at once in 17.4KB LDS, ONE barrier
//  staged   -> R11 per-channel restage (5 barriers)
//  fallback -> direct global f2 gathers (large scale)
__global__ __launch_bounds__(256, 8) void affine_sample_kernel(
    const float* __restrict__ x,
    const float4* __restrict__ cf,
    float* __restrict__ out)
{
    __shared__ float smem[SMEMF];                // 17408 B -> 8 blocks/CU

    int tid  = threadIdx.x;
    int lane = tid & 63;
    int wid  = tid >> 6;
    int strip = lane & 7;
    int lrow  = lane >> 3;

    int bidx = blockIdx.x;          // [b:6][tile:8]
    int b    = bidx >> 8;
    int rem  = bidx & 255;
    int tileH = (rem >> 4) << 5;
    int tileW = (rem & 15) << 5;

    int h  = tileH + (wid << 3) + lrow;
    int w0 = tileW + (strip << 2);

    float4 k = cf[b];
    float ct = k.x, st = k.y, Cx = k.z, Cy = k.w;

    // ---- block-uniform source bbox from tile corners
    float wA = (float)tileW, wB = (float)(tileW + 31);
    float hA = (float)tileH, hB = (float)(tileH + 31);
    float cwA = ct * wA, cwB = ct * wB, shA = st * hA, shB = st * hB;
    float ixmin = fminf(cwA, cwB) - fmaxf(shA, shB) + Cx;
    float ixmax = fmaxf(cwA, cwB) - fminf(shA, shB) + Cx;
    float swA = st * wA, swB = st * wB, chA = ct * hA, chB = ct * hB;
    float iymin = fminf(swA, swB) + fminf(chA, chB) + Cy;
    float iymax = fmaxf(swA, swB) + fmaxf(chA, chB) + Cy;

    int bx_lo = (int)floorf(ixmin) - 1;          // +-1: ulp-drift margin
    int bx_hi = (int)floorf(ixmax) + 2;
    int by_lo = (int)floorf(iymin) - 1;
    int by_hi = (int)floorf(iymax) + 2;

    float* ob = out + b * CHW + h * WW + w0;

    // ---- class 1: fully out-of-bounds -> exact zeros
    bool oob = (bx_hi <= 0) | (bx_lo >= WW - 1) | (by_hi <= 0) | (by_lo >= HH - 1);
    if (oob) {
        const f4_t z = {0.0f, 0.0f, 0.0f, 0.0f};
#pragma unroll
        for (int ch = 0; ch < CC; ++ch)
            __builtin_nontemporal_store(z, (f4_t*)(ob + ch * HW));
        return;
    }

    // ---- class 2 modifier: fully interior -> clamp/mask-free weights
    bool interior = (bx_lo >= 0) & (bx_hi <= WW - 1) & (by_lo >= 0) & (by_hi <= HH - 1);

    int px_lo = min(max(bx_lo, 0), WW - 2);
    int px_hi = min(max(bx_hi - 1, 0), WW - 2) + 1;
    int py_lo = min(max(by_lo, 0), HH - 2);
    int py_hi = min(max(by_hi - 1, 0), HH - 2) + 1;
    int By = py_hi - py_lo + 1;

    int ax_lo = px_lo & ~3;                      // 16B-aligned window start
    int span  = px_hi - ax_lo;                   // cols needed minus 1
    bool staged = (span <= 63) && (By <= PROWS);
    int BxA = (span | 3) + 1;                    // tight width, mult of 4, <=64
    if (ax_lo + BxA > WW) ax_lo = WW - BxA;      // keep window in-bounds (aligned)

    // compact: all 3 channels fit in LDS at once -> single barrier
    int SSTR = BxA + 4;                          // mult of 4, != 0 mod 32 spread
    int cpc  = By * SSTR;                        // floats per channel
    bool compact = staged && (3 * cpc <= SMEMF);
    int lstr = compact ? SSTR : PSTRIDE;

    const float* plane0 = x + b * CHW;
    const float* srcb   = plane0 + py_lo * WW + ax_lo;

    int r0 = tid >> 4;                           // 0..15 staging row
    int c4 = (tid & 15) << 2;                    // 0,4,...,60 staging col

    bool cok = c4 < BxA;                         // tight width guard
    bool g0 = cok & (r0      < By);
    bool g1 = cok & (r0 + 16 < By);
    bool g2 = cok & (r0 + 32 < By);
    bool g3 = cok & (r0 + 48 < By);

    // burst staging: 4 loads in flight, then 4 ds_writes; temps die here
    auto burst = [&](const float* s, float* dst, int stride) {
        f4_t t0 = {0,0,0,0}, t1 = {0,0,0,0}, t2 = {0,0,0,0}, t3 = {0,0,0,0};
        if (g0) t0 = *(const f4_t*)(s +  r0       * WW + c4);
        if (g1) t1 = *(const f4_t*)(s + (r0 + 16) * WW + c4);
        if (g2) t2 = *(const f4_t*)(s + (r0 + 32) * WW + c4);
        if (g3) t3 = *(const f4_t*)(s + (r0 + 48) * WW + c4);
        if (g0) *(f4_t*)(dst +  r0       * stride + c4) = t0;
        if (g1) *(f4_t*)(dst + (r0 + 16) * stride + c4) = t1;
        if (g2) *(f4_t*)(dst + (r0 + 32) * stride + c4) = t2;
        if (g3) *(f4_t*)(dst + (r0 + 48) * stride + c4) = t3;
    };

    // ---- per-pixel geometry (incremental along the 4-px strip; shared by 3 ch)
    float ix = ct * (float)w0 - st * (float)h + Cx;
    float iy = st * (float)w0 + ct * (float)h + Cy;

    float al[4], ar[4], f0[4], f1[4];
    int o0[4], o1[4];

    if (interior) {
#pragma unroll
        for (int p = 0; p < 4; ++p) {
            float x0f = floorf(ix), y0f = floorf(iy);
            float fx = ix - x0f,    fy = iy - y0f;
            int x0 = (int)x0f, y0 = (int)y0f;
            al[p] = 1.0f - fx;
            ar[p] = fx;
            f0[p] = 1.0f - fy;
            f1[p] = fy;
            if (staged) {
                int lx = x0 - ax_lo;
                o0[p] = (y0     - py_lo) * lstr + lx;
                o1[p] = (y0 + 1 - py_lo) * lstr + lx;
            } else {
                o0[p] =  y0      * WW + x0;
                o1[p] = (y0 + 1) * WW + x0;
            }
            ix += ct;
            iy += st;
        }
    } else {
#pragma unroll
        for (int p = 0; p < 4; ++p) {
            float x0f = floorf(ix), y0f = floorf(iy);
            float fx = ix - x0f,    fy = iy - y0f;
            int x0 = (int)x0f, y0 = (int)y0f;
            int y1 = y0 + 1;

            bool xin = (x0 >= 0) & (x0 <= WW - 2);
            float wl = 1.0f - fx;
            al[p] = xin ? wl : ((x0 == -1)     ? fx : 0.0f);
            ar[p] = xin ? fx : ((x0 == WW - 1) ? wl : 0.0f);
            int base = min(max(x0, 0), WW - 2);

            bool vy0 = (y0 >= 0) & (y0 < HH);
            bool vy1 = (y1 >= 0) & (y1 < HH);
            int y0c = min(max(y0, 0), HH - 1);
            int y1c = min(max(y1, 0), HH - 1);
            f0[p] = (1.0f - fy) * (float)vy0;
            f1[p] = fy          * (float)vy1;

            if (staged) {
                int lx = base - ax_lo;
                o0[p] = (y0c - py_lo) * lstr + lx;
                o1[p] = (y1c - py_lo) * lstr + lx;
            } else {
                o0[p] = y0c * WW + base;
                o1[p] = y1c * WW + base;
            }
            ix += ct;
            iy += st;
        }
    }

    if (compact) {
        // ---- stage ALL 3 channels, one barrier, blend with no further syncs
        burst(srcb,          &smem[0],       SSTR);
        burst(srcb + HW,     &smem[cpc],     SSTR);
        burst(srcb + 2 * HW, &smem[2 * cpc], SSTR);
        __syncthreads();
#pragma unroll
        for (int ch = 0; ch < CC; ++ch) {
            const float* pl = &smem[ch * cpc];
            f4_t v;
#pragma unroll
            for (int p = 0; p < 4; ++p) {
                float a0 = pl[o0[p]], a1 = pl[o0[p] + 1];
                float b0 = pl[o1[p]], b1 = pl[o1[p] + 1];
                v[p] = f0[p] * (al[p] * a0 + ar[p] * a1)
                     + f1[p] * (al[p] * b0 + ar[p] * b1);
            }
            __builtin_nontemporal_store(v, (f4_t*)(ob + ch * HW));
        }
    } else if (staged) {
        // ---- R11 per-channel restage (bbox too big for 3-at-once)
#pragma unroll
        for (int ch = 0; ch < CC; ++ch) {
            if (ch) __syncthreads();             // previous blend's reads done
            burst(srcb + ch * HW, smem, PSTRIDE);
            __syncthreads();                     // patch ready

            f4_t v;
#pragma unroll
            for (int p = 0; p < 4; ++p) {
                float a0 = smem[o0[p]], a1 = smem[o0[p] + 1];
                float b0 = smem[o1[p]], b1 = smem[o1[p] + 1];
                v[p] = f0[p] * (al[p] * a0 + ar[p] * a1)
                     + f1[p] * (al[p] * b0 + ar[p] * b1);
            }
            __builtin_nontemporal_store(v, (f4_t*)(ob + ch * HW));
        }
    } else {
        // ---- fallback: direct global f2 gathers (large scale, no barriers)
#pragma unroll
        for (int ch = 0; ch < CC; ++ch) {
            const float* pl = plane0 + ch * HW;
            f4_t v;
#pragma unroll
            for (int p = 0; p < 4; ++p) {
                f2_t t = *(const f2_t*)(pl + o0[p]);
                f2_t u = *(const f2_t*)(pl + o1[p]);
                v[p] = f0[p] * (al[p] * t.x + ar[p] * t.y)
                     + f1[p] * (al[p] * u.x + ar[p] * u.y);
            }
            __builtin_nontemporal_store(v, (f4_t*)(ob + ch * HW));
        }
    }
}

extern "C" void kernel_launch(void* const* d_in, const int* in_sizes, int n_in,
                              void* d_out, int out_size, void* d_ws, size_t ws_size,
                              hipStream_t stream)
{
    const float* x  = (const float*)d_in[0];
    const float* mp = (const float*)d_in[1];
    float* out = (float*)d_out;
    float4* cf = (float4*)d_ws;     // 1 KB scratch

    prep_kernel<<<1, 64, 0, stream>>>(mp, cf);
    dim3 block(256);
    dim3 grid(BB * 256);            // 64 batches x 16x16 tiles of 32x32
    affine_sample_kernel<<<grid, block, 0, stream>>>(x, cf, out);
}